// Round 11
// baseline (1798.911 us; speedup 1.0000x reference)
//
#include <hip/hip_runtime.h>

// ---------------- problem constants ----------------
#define Hd   256
#define Bd   16
#define Td   128
#define Ld   50
#define Vd   32000
#define G5H  1280     // 5*H

typedef __attribute__((ext_vector_type(8))) short short8v;  // 8 bf16 (4 VGPRs)
typedef __attribute__((ext_vector_type(4))) float f32x4;

__device__ __forceinline__ unsigned short f2bu(float f) {   // f32 -> bf16 bits (RNE)
  unsigned u = __float_as_uint(f);
  unsigned r = (u + 0x7fffu + ((u >> 16) & 1u)) >> 16;
  return (unsigned short)r;
}
__device__ __forceinline__ float bu2f(unsigned short b) {
  return __uint_as_float(((unsigned)b) << 16);
}
__device__ __forceinline__ float sigm(float x) { return 1.f / (1.f + __expf(-x)); }

// agent-scope (MALL) relaxed 8B atomics — proven cross-XCD path
__device__ __forceinline__ void st_devd(double* p, double v) {
  __hip_atomic_store(p, v, __ATOMIC_RELAXED, __HIP_MEMORY_SCOPE_AGENT);
}
__device__ __forceinline__ double ld_devd(const double* p) {
  return __hip_atomic_load((double*)p, __ATOMIC_RELAXED, __HIP_MEMORY_SCOPE_AGENT);
}
__device__ __forceinline__ double pk2(float a, float b) {
  union { double d; float2 f; } u; u.f = make_float2(a, b); return u.d;
}

// ---------------- fp32 -> bf16 conversion + MFMA fragment packing ----------------
__global__ __launch_bounds__(256) void conv_kernel(
    const float* __restrict__ wv, const float* __restrict__ w_ih,
    const float* __restrict__ fcW, const float* __restrict__ w_hh,
    const float* __restrict__ Zm, const float* __restrict__ Pm,
    unsigned short* __restrict__ wv_b, unsigned short* __restrict__ wih_b,
    unsigned short* __restrict__ fcw_b, unsigned short* __restrict__ whh_f,
    unsigned short* __restrict__ z_f, unsigned short* __restrict__ p_f)
{
  const long N0 = 2048000, N1 = N0 + 81920, N2 = N1 + 2048000;
  const long NW = 81920, NZ = 16384, NP = 16384;         // frag float4-groups
  const long N5 = N2 + NW + NZ + NP;
  for (long idx = (long)blockIdx.x * blockDim.x + threadIdx.x; idx < N5;
       idx += (long)gridDim.x * blockDim.x) {
    if (idx < N2) {                                      // plain copies
      const float* src; unsigned short* dst; long off;
      if      (idx < N0) { src = wv;   dst = wv_b;  off = idx; }
      else if (idx < N1) { src = w_ih; dst = wih_b; off = idx - N0; }
      else               { src = fcW;  dst = fcw_b; off = idx - N1; }
      float4 v = *(const float4*)(src + off * 4);
      ushort4 o;
      o.x = f2bu(v.x); o.y = f2bu(v.y); o.z = f2bu(v.z); o.w = f2bu(v.w);
      *(ushort4*)(dst + off * 4) = o;
    } else {                                             // fragment packing
      long u = idx - N2;
      const float* src; unsigned short* dst;
      if      (u < NW)      { src = w_hh; dst = whh_f; }
      else if (u < NW + NZ) { src = Zm;   dst = z_f;  u -= NW; }
      else                  { src = Pm;   dst = p_f;  u -= NW + NZ; }
      long frag = u >> 7;                 // 128 float4-groups per 512-short frag
      int g128 = (int)(u & 127);
      int lane = g128 >> 1, e0 = (g128 & 1) * 4;
      long T = frag >> 3; int ks = (int)(frag & 7);
      int lr = lane & 15, lg = lane >> 4;
      float4 v = *(const float4*)(src + (T * 16 + lr) * 256 + ks * 32 + lg * 8 + e0);
      ushort4 o;
      o.x = f2bu(v.x); o.y = f2bu(v.y); o.z = f2bu(v.z); o.w = f2bu(v.w);
      *(ushort4*)(dst + u * 4) = o;
    }
  }
}

// ---------------- per-batch prep: goal embed, ht0, goal_term, E, sumE ----------------
__global__ __launch_bounds__(256) void prep_kernel(
    const int* __restrict__ g, const int* __restrict__ ingr,
    const float* __restrict__ wv, const float* __restrict__ Ug,
    const float* __restrict__ Ym, const float* __restrict__ yb,
    float* __restrict__ E_ws, float* __restrict__ sumE,
    float* __restrict__ goal_ws, float* __restrict__ HT0)
{
  __shared__ float ge[256];
  const int b = blockIdx.x, tid = threadIdx.x;
  float s = 0.f;
  for (int i = 0; i < 8; ++i) s += wv[((size_t)g[(b << 3) + i] << 8) + tid];
  ge[tid] = s;
  __syncthreads();
  float h0 = 0.f, gt = 0.f;
  const float* ur = Ug + (tid << 8);
  const float* yr = Ym + (tid << 8);
#pragma unroll 8
  for (int k = 0; k < Hd; k += 4) {
    float4 gv = *(const float4*)(ge + k);
    float4 uv = *(const float4*)(ur + k);
    float4 yv = *(const float4*)(yr + k);
    h0 = fmaf(gv.x, uv.x, h0); h0 = fmaf(gv.y, uv.y, h0);
    h0 = fmaf(gv.z, uv.z, h0); h0 = fmaf(gv.w, uv.w, h0);
    gt = fmaf(gv.x, yv.x, gt); gt = fmaf(gv.y, yv.y, gt);
    gt = fmaf(gv.z, yv.z, gt); gt = fmaf(gv.w, yv.w, gt);
  }
  HT0[(b << 8) + tid] = h0;                    // [b][c]
  goal_ws[(b << 8) + tid] = gt + yb[tid];      // [b][c]
  float se = 0.f;
  for (int l = 0; l < Ld; ++l) {
    float v = wv[((size_t)ingr[b * Ld + l] << 8) + tid];
    E_ws[((size_t)(b * Ld + l) << 8) + tid] = v;
    se += v;
  }
  sumE[(b << 8) + tid] = se;                   // [b][k]
}

// ---------------- bf16 MFMA GEMM (128x128 tile, K=256), two epilogues ----------------
template <int MODE>
__global__ __launch_bounds__(256) void gemm_bf16(
    const unsigned short* __restrict__ A, const unsigned short* __restrict__ Bmat,
    const int* __restrict__ ridx, const float* __restrict__ bias,
    float* __restrict__ C)
{
  __shared__ unsigned short As[128 * 64];
  __shared__ unsigned short Bs[128 * 64];
  const int tid = threadIdx.x;
  const int m0 = blockIdx.x << 7, n0 = blockIdx.y << 7;
  const int wave = tid >> 6, lane = tid & 63;
  const int wm = wave >> 1, wn = wave & 1;
  const int lr = lane & 15, lg = lane >> 4;

  f32x4 acc[4][4];
#pragma unroll
  for (int i = 0; i < 4; ++i)
#pragma unroll
    for (int jj = 0; jj < 4; ++jj) acc[i][jj] = (f32x4){0.f, 0.f, 0.f, 0.f};

  const int srow = tid >> 1, shalf = tid & 1;
  const unsigned short* arow;
  {
    int gm = m0 + srow;
    if (MODE == 0) {
      int tt = gm >> 4, bb = gm & 15;
      arow = A + (size_t)ridx[bb * Td + tt] * Hd;
    } else {
      arow = A + (size_t)gm * Hd;
    }
  }
  const unsigned short* brow = Bmat + (size_t)(n0 + srow) * Hd;

  for (int k0 = 0; k0 < Hd; k0 += 64) {
#pragma unroll
    for (int c = 0; c < 4; ++c) {
      int k = shalf * 32 + c * 8;
      uint4 va = *(const uint4*)(arow + k0 + k);
      uint4 vb = *(const uint4*)(brow + k0 + k);
      int byo = (srow << 7) + ((k << 1) ^ ((srow & 7) << 4));  // XOR swizzle
      *(uint4*)((char*)As + byo) = va;
      *(uint4*)((char*)Bs + byo) = vb;
    }
    __syncthreads();
#pragma unroll
    for (int kk = 0; kk < 2; ++kk) {
      short8v af[4], bfr[4];
      const int kb = kk * 32 + lg * 8;
#pragma unroll
      for (int i = 0; i < 4; ++i) {
        int ar = wm * 64 + i * 16 + lr;
        af[i] = *(const short8v*)((const char*)As + (ar << 7) + ((kb << 1) ^ ((ar & 7) << 4)));
        int br = wn * 64 + i * 16 + lr;
        bfr[i] = *(const short8v*)((const char*)Bs + (br << 7) + ((kb << 1) ^ ((br & 7) << 4)));
      }
#pragma unroll
      for (int i = 0; i < 4; ++i)
#pragma unroll
        for (int jj = 0; jj < 4; ++jj)
          acc[i][jj] = __builtin_amdgcn_mfma_f32_16x16x32_bf16(af[i], bfr[jj], acc[i][jj], 0, 0, 0);
    }
    __syncthreads();
  }
#pragma unroll
  for (int i = 0; i < 4; ++i)
#pragma unroll
    for (int jj = 0; jj < 4; ++jj) {
      int col = n0 + wn * 64 + jj * 16 + lr;
      float bv = bias[col];
#pragma unroll
      for (int r = 0; r < 4; ++r) {
        int row = m0 + wm * 64 + i * 16 + lg * 4 + r;
        float v = acc[i][jj][r] + bv;
        if (MODE == 0) {
          int tt = row >> 4, bb = row & 15;
          C[((size_t)(bb * Td + tt)) * G5H + col] = v;   // gi[b][t][grow]
        } else {
          C[(size_t)row * Vd + col] = v;
        }
      }
    }
}

// ---------------- recurrence v11: tagged self-validating payloads, no flags ----------------
// 8 WGs per batch (b = idx>>3, j = idx&7). Every published float is pk2(value,
// tag=t+1): consumers gather with per-element retry-until-tag loops. No drain,
// no flag store, no poll phase. Parity double-buffer; producer lead capped at 2
// steps by the gather dependency; launcher memsets tags to 0 (replay-safe).
#define RNN_SMEM 149440
__global__ __launch_bounds__(256, 1) void rnn_kernel(
    const unsigned short* __restrict__ whh_f, const unsigned short* __restrict__ z_f,
    const unsigned short* __restrict__ p_f, const float* __restrict__ b_hh,
    const float* __restrict__ Sm, const float* __restrict__ z_bias,
    const float* __restrict__ gi, const float* __restrict__ goal_ws,
    const float* __restrict__ E_ws, const float* __restrict__ sumE,
    const float* __restrict__ HT0,
    unsigned short* __restrict__ out_all, float* __restrict__ d_out,
    double* __restrict__ XBH, double* __restrict__ XBP)
{
  extern __shared__ char smem[];
  unsigned short* w_lds = (unsigned short*)(smem);            // 10 tiles*8ks*512
  unsigned short* z_lds = (unsigned short*)(smem + 81920);    // 2*8*512
  unsigned short* p_lds = (unsigned short*)(smem + 98304);    // 16*512 (ks=j)
  unsigned short* E_lds = (unsigned short*)(smem + 114688);   // 50*264 (chunk-pad)
  float* hrow  = (float*)(smem + 141088);   // 256 fp32 ht (current, full)
  float* hp    = (float*)(smem + 142112);   // 256 h_proj (full, summed)
  float* gh    = (float*)(smem + 143136);   // 160 (g*32+cl)
  float* zd    = (float*)(smem + 143776);   // 32
  float* se    = (float*)(smem + 143904);   // 256
  float* gl    = (float*)(smem + 144928);   // 32 (goal_term slice)
  float* bh    = (float*)(smem + 145056);   // 160
  float* zb    = (float*)(smem + 145696);   // 32
  float* a_l   = (float*)(smem + 145824);   // 64
  float* d_l   = (float*)(smem + 146080);   // 64
  float* an_l  = (float*)(smem + 146336);   // 64
  float* au_l  = (float*)(smem + 146592);   // 64
  float* sd    = (float*)(smem + 146848);   // 4
  float* refl  = (float*)(smem + 146864);   // 4
  unsigned short* ht_hi = (unsigned short*)(smem + 146880);   // 256
  unsigned short* ht_lo = (unsigned short*)(smem + 147392);   // 256
  unsigned short* tp_hi = (unsigned short*)(smem + 147904);   // 256
  unsigned short* tp_lo = (unsigned short*)(smem + 148416);   // 256
  unsigned short* hs_hi = (unsigned short*)(smem + 148928);   // 32 (ht2 slice)
  unsigned short* hs_lo = (unsigned short*)(smem + 148992);   // 32
  float* Sl    = (float*)(smem + 149056);   // 96 (S slice [3][32])

  const int b  = blockIdx.x >> 3;
  const int j  = blockIdx.x & 7;
  const int hc0 = j << 5;
  const int tid = threadIdx.x;
  const int lane = tid & 63, wid = tid >> 6;
  const int lr = lane & 15, lg = lane >> 4;

  // ---- one-time staging ----
  for (int idx = tid; idx < 5120; idx += 256) {        // w_hh slice (uint4 units)
    int f = idx >> 6, e = idx & 63;
    int q = f >> 3, ks = f & 7;
    int T = (q >> 1) * 16 + 2 * j + (q & 1);
    *(uint4*)(w_lds + ((size_t)f << 9) + e * 8) =
        *(const uint4*)(whh_f + (((size_t)T * 8 + ks) << 9) + e * 8);
  }
  for (int idx = tid; idx < 1024; idx += 256) {        // Z slice
    int f = idx >> 6, e = idx & 63;
    int q = f >> 3, ks = f & 7;
    int T = 2 * j + q;
    *(uint4*)(z_lds + ((size_t)f << 9) + e * 8) =
        *(const uint4*)(z_f + (((size_t)T * 8 + ks) << 9) + e * 8);
  }
  for (int idx = tid; idx < 1024; idx += 256) {        // P column-slice (ks=j)
    int f = idx >> 6, e = idx & 63;
    *(uint4*)(p_lds + ((size_t)f << 9) + e * 8) =
        *(const uint4*)(p_f + (((size_t)f * 8 + j) << 9) + e * 8);
  }
  for (int idx = tid; idx < Ld * 256; idx += 256) {    // E bf16, chunk-padded rows
    int l = idx >> 8, k = idx & 255;
    E_lds[l * 264 + k + 2 * (k >> 6)] = f2bu(E_ws[((size_t)(b * Ld + l) << 8) + k]);
  }
  if (tid < 160) bh[tid] = b_hh[((tid >> 5) << 8) + hc0 + (tid & 31)];
  if (tid < 96) Sl[tid] = Sm[((tid >> 5) << 8) + hc0 + (tid & 31)];
  if (tid < 32) {
    gl[tid] = goal_ws[(b << 8) + hc0 + tid];
    zb[tid] = z_bias[hc0 + tid];
  }
  if (tid < 256) {
    float s0 = sumE[(b << 8) + tid];
    se[tid] = s0;
    unsigned short hi = f2bu(s0);
    tp_hi[tid] = hi; tp_lo[tid] = f2bu(s0 - bu2f(hi));
    float h0 = HT0[(b << 8) + tid];
    hrow[tid] = h0;
    unsigned short hh = f2bu(h0);
    ht_hi[tid] = hh; ht_lo[tid] = f2bu(h0 - bu2f(hh));
  }
  if (tid < 64) a_l[tid] = 0.f;
  __syncthreads();

  for (int t = 0; t < Td; ++t) {
    const int par = t & 1;
    double* htpub = XBH + ((size_t)((par * 16 + b) * 8 + j)) * 32;
    const double* htr = XBH + ((size_t)((par * 16 + b) * 8)) * 32;
    double* hppub = XBP + ((size_t)((par * 16 + b) * 8 + j)) * 260;
    const double* hpr = XBP + ((size_t)((par * 16 + b) * 8)) * 260;
    const unsigned tagu = (unsigned)(t + 1);
    const float tagf = __uint_as_float(tagu);
    // ---- gi prefetch (tid<32), hides under A1 ----
    float g_ir = 0.f, g_iu = 0.f, g_in = 0.f, g_ig = 0.f, g_ii = 0.f;
    if (tid < 32) {
      const float* gib = gi + ((size_t)(b * Td + t)) * G5H + hc0 + tid;
      g_ir = gib[0];    g_iu = gib[256];  g_in = gib[512];
      g_ig = gib[768];  g_ii = gib[1024];
    }
    // ========== A1: gh (10 tiles) + zd (2 tiles), 3 tiles/wave ==========
#pragma unroll
    for (int ti = 0; ti < 3; ++ti) {
      int q = wid * 3 + ti;
      const unsigned short* base = (q < 10) ? (w_lds + ((size_t)(q * 8) << 9))
                                            : (z_lds + ((size_t)((q - 10) * 8) << 9));
      const unsigned short* shi = (q < 10) ? ht_hi : tp_hi;
      const unsigned short* slo = (q < 10) ? ht_lo : tp_lo;
      f32x4 acc = (f32x4){0.f, 0.f, 0.f, 0.f};
#pragma unroll
      for (int ks = 0; ks < 8; ++ks) {
        short8v av = *(const short8v*)(base + ((size_t)ks << 9) + (lane << 3));
        short8v bv = (short8v){0, 0, 0, 0, 0, 0, 0, 0};
        if (lr < 2)
          bv = *(const short8v*)((lr == 0 ? shi : slo) + ks * 32 + (lg << 3));
        acc = __builtin_amdgcn_mfma_f32_16x16x32_bf16(av, bv, acc, 0, 0, 0);
      }
#pragma unroll
      for (int r = 0; r < 4; ++r) {
        float v = acc[r] + __shfl_xor(acc[r], 1);        // col0(hi)+col1(lo)
        if (lr == 0) {
          int row = q * 16 + lg * 4 + r;
          if (q < 10) gh[row] = v; else zd[row - 160] = v;
        }
      }
    }
    __syncthreads();
    // ========== A2: gates -> ht2 slice + sd partials; publish tagged ==========
    if (tid < 32) {
      int cl = tid;
      float hr = gh[cl]       + bh[cl];
      float hu = gh[32 + cl]  + bh[32 + cl];
      float hn = gh[64 + cl]  + bh[64 + cl];
      float hg = gh[96 + cl]  + bh[96 + cl];
      float hq = gh[128 + cl] + bh[128 + cl];
      float rt = sigm(g_ir + hr), zt = sigm(g_iu + hu);
      float st = sigm(g_ig + hg), qt = sigm(g_ii + hq);
      float htl = tanhf(g_in + rt * hn + st * gl[cl] + qt * (zd[cl] + zb[cl]));
      float prev = hrow[hc0 + cl];
      float h2 = htl + zt * (prev - htl);
      unsigned short hi = f2bu(h2);
      hs_hi[cl] = hi; hs_lo[cl] = f2bu(h2 - bu2f(hi));
      st_devd(htpub + cl, pk2(h2, tagf));                // tagged ht2 slice
      // sd partials over this 32-col slice (3 dots, 32-lane reduce)
      float p0 = Sl[cl] * h2, p1 = Sl[32 + cl] * h2, p2 = Sl[64 + cl] * h2;
      p0 += __shfl_xor(p0, 1);  p0 += __shfl_xor(p0, 2);  p0 += __shfl_xor(p0, 4);
      p0 += __shfl_xor(p0, 8);  p0 += __shfl_xor(p0, 16);
      p1 += __shfl_xor(p1, 1);  p1 += __shfl_xor(p1, 2);  p1 += __shfl_xor(p1, 4);
      p1 += __shfl_xor(p1, 8);  p1 += __shfl_xor(p1, 16);
      p2 += __shfl_xor(p2, 1);  p2 += __shfl_xor(p2, 2);  p2 += __shfl_xor(p2, 4);
      p2 += __shfl_xor(p2, 8);  p2 += __shfl_xor(p2, 16);
      if (cl == 0) {
        st_devd(hppub + 256, pk2(p0, tagf));
        st_devd(hppub + 257, pk2(p1, tagf));
        st_devd(hppub + 258, pk2(p2, tagf));
      }
    }
    __syncthreads();
    // ========== A3: h_proj partial (16 tiles, K=32) -> publish tagged ==========
#pragma unroll
    for (int ti = 0; ti < 4; ++ti) {
      int q = wid * 4 + ti;
      short8v av = *(const short8v*)(p_lds + ((size_t)q << 9) + (lane << 3));
      short8v bv = (short8v){0, 0, 0, 0, 0, 0, 0, 0};
      if (lr < 2)
        bv = *(const short8v*)((lr == 0 ? hs_hi : hs_lo) + (lg << 3));
      f32x4 acc = (f32x4){0.f, 0.f, 0.f, 0.f};
      acc = __builtin_amdgcn_mfma_f32_16x16x32_bf16(av, bv, acc, 0, 0, 0);
      float vv[4];
#pragma unroll
      for (int r = 0; r < 4; ++r) vv[r] = acc[r] + __shfl_xor(acc[r], 1);
      if (lr == 0) {
        int row = q * 16 + lg * 4;
        st_devd(hppub + row + 0, pk2(vv[0], tagf));
        st_devd(hppub + row + 1, pk2(vv[1], tagf));
        st_devd(hppub + row + 2, pk2(vv[2], tagf));
        st_devd(hppub + row + 3, pk2(vv[3], tagf));
      }
    }
    // ========== GATH-P: tagged gather of hp (j-ascending) + sd; retry-per-elem ==========
    {
      int e = tid;
      float v[8];
      bool got[8];
#pragma unroll
      for (int js = 0; js < 8; ++js) got[js] = false;
      int guard = 0;
      while (1) {
        bool ok = true;
#pragma unroll
        for (int js = 0; js < 8; ++js) {
          if (!got[js]) {
            union { double d; float2 f; } u;
            u.d = ld_devd(hpr + (size_t)js * 260 + e);
            if (__float_as_uint(u.f.y) == tagu) { v[js] = u.f.x; got[js] = true; }
            else ok = false;
          }
        }
        if (ok) break;
        __builtin_amdgcn_s_sleep(1);
        if (++guard > (1 << 20)) break;
      }
      hp[e] = ((((((v[0] + v[1]) + v[2]) + v[3]) + v[4]) + v[5]) + v[6]) + v[7];
      if (tid >= 253) {                                  // sd gather (3 threads)
        int w = tid - 253;
        float sv[8];
        bool sgot[8];
#pragma unroll
        for (int js = 0; js < 8; ++js) sgot[js] = false;
        int g2 = 0;
        while (1) {
          bool ok = true;
#pragma unroll
          for (int js = 0; js < 8; ++js) {
            if (!sgot[js]) {
              union { double d; float2 f; } u;
              u.d = ld_devd(hpr + (size_t)js * 260 + 256 + w);
              if (__float_as_uint(u.f.y) == tagu) { sv[js] = u.f.x; sgot[js] = true; }
              else ok = false;
            }
          }
          if (ok) break;
          __builtin_amdgcn_s_sleep(1);
          if (++g2 > (1 << 20)) break;
        }
        sd[w] = ((((((sv[0] + sv[1]) + sv[2]) + sv[3]) + sv[4]) + sv[5]) + sv[6]) + sv[7];
      }
    }
    __syncthreads();
    // ========== D2: E-dots + ref softmax ==========
    if (tid < 200) {
      int l = tid >> 2, q = tid & 3;
      const unsigned short* er = E_lds + l * 264 + q * 66;   // chunk-pad: no conflict
      const float* hq = hp + (q << 6);
      float p = 0.f;
#pragma unroll 8
      for (int i = 0; i < 32; ++i) {
        unsigned uu = *(const unsigned*)(er + 2 * i);
        float e0 = __uint_as_float(uu << 16);
        float e1 = __uint_as_float(uu & 0xffff0000u);
        p = fmaf(e0, hq[2 * i], p);
        p = fmaf(e1, hq[2 * i + 1], p);
      }
      p += __shfl_xor(p, 1); p += __shfl_xor(p, 2);
      if (q == 0) d_l[l] = p;
    } else if (tid == 224) {                        // ref = softmax(BETA*sd)
      float s0 = 5.0f * sd[0], s1 = 5.0f * sd[1], s2 = 5.0f * sd[2];
      float m = fmaxf(s0, fmaxf(s1, s2));
      float e0 = __expf(s0 - m), e1 = __expf(s1 - m), e2 = __expf(s2 - m);
      float inv = 1.f / (e0 + e1 + e2);
      refl[0] = e0 * inv; refl[1] = e1 * inv; refl[2] = e2 * inv;
    }
    __syncthreads();
    // ========== E: alphas (tid<128) || GATH-H tagged (tid>=128) ==========
    if (tid < 128) {
      int which = tid >> 6;
      int l = tid & 63;
      float dv;
      if (which == 0) dv = (l < Ld) ? 2.0f * (1.f - a_l[l]) * d_l[l] : -3.4e38f;
      else            dv = (l < Ld) ? 2.0f * a_l[l] * d_l[l]         : -3.4e38f;
      float m = dv;
      m = fmaxf(m, __shfl_xor(m, 1));  m = fmaxf(m, __shfl_xor(m, 2));
      m = fmaxf(m, __shfl_xor(m, 4));  m = fmaxf(m, __shfl_xor(m, 8));
      m = fmaxf(m, __shfl_xor(m, 16)); m = fmaxf(m, __shfl_xor(m, 32));
      float e = (l < Ld) ? __expf(dv - m) : 0.f;
      float ss = e;
      ss += __shfl_xor(ss, 1);  ss += __shfl_xor(ss, 2);  ss += __shfl_xor(ss, 4);
      ss += __shfl_xor(ss, 8);  ss += __shfl_xor(ss, 16); ss += __shfl_xor(ss, 32);
      float al = e / ss;
      if (which == 0) an_l[l] = al; else au_l[l] = al;
    } else {
      int idx = tid - 128;                          // 0..127 -> cols 2idx, 2idx+1
      int c0 = idx << 1;
      float a0, a1;
      int guard = 0;
      while (1) {
        union { double d; float2 f; } u0, u1;
        u0.d = ld_devd(htr + c0);
        u1.d = ld_devd(htr + c0 + 1);
        a0 = u0.f.x; a1 = u1.f.x;
        if (__float_as_uint(u0.f.y) == tagu && __float_as_uint(u1.f.y) == tagu) break;
        __builtin_amdgcn_s_sleep(1);
        if (++guard > (1 << 20)) break;
      }
      hrow[c0] = a0; hrow[c0 + 1] = a1;
      unsigned short h0 = f2bu(a0), h1 = f2bu(a1);
      ht_hi[c0] = h0;     ht_lo[c0] = f2bu(a0 - bu2f(h0));
      ht_hi[c0 + 1] = h1; ht_lo[c0 + 1] = f2bu(a1 - bu2f(h1));
      if (t == Td - 1 && j == 0) {
        d_out[(size_t)65536000 + (b << 8) + c0] = a0;
        d_out[(size_t)65536000 + (b << 8) + c0 + 1] = a1;
      }
    }
    __syncthreads();
    // ========== F: c_n, c_u, out, tmp(t+1)  (replicated; WG0 stores) ==========
    {
      int k = tid;
      int kp = k + 2 * (k >> 6);                   // chunk-padded E index
      float accn = 0.f, accu = 0.f, acct = 0.f;
#pragma unroll 10
      for (int l = 0; l < Ld; ++l) {
        float e = bu2f(E_lds[l * 264 + kp]);
        accn = fmaf(an_l[l], e, accn);
        accu = fmaf(au_l[l], e, accu);
        acct = fmaf(a_l[l], e, acct);              // a BEFORE this step's update
      }
      float outv = refl[0] * hp[k] + refl[1] * accn + refl[2] * accu;
      float tn = se[k] - acct;                     // tmp(t+1) = sum((1-a)*E)
      unsigned short th = f2bu(tn);
      tp_hi[k] = th; tp_lo[k] = f2bu(tn - bu2f(th));
      if (j == 0) {
        out_all[(((b << 7) + t) << 8) + k] = f2bu(outv);
        if (t == Td - 1) {
          for (int l = 0; l < Ld; ++l) {           // E_new = (1-a_pre)*E
            size_t o = ((size_t)(b * Ld + l) << 8) + k;
            d_out[(size_t)65540896 + o] = (1.f - a_l[l]) * E_ws[o];
          }
        }
      }
    }
    __syncthreads();
    // ========== G: a update (no trailing barrier: next reader is E(t+1)) ==========
    if (tid < Ld) {
      float na = a_l[tid] + refl[1] * an_l[tid];
      a_l[tid] = na;
      if (t == Td - 1 && j == 0) d_out[(size_t)65540096 + b * Ld + tid] = na;
    }
  }
}

// ---------------- host launcher ----------------
extern "C" void kernel_launch(void* const* d_in, const int* in_sizes, int n_in,
                              void* d_out, int out_size, void* d_ws, size_t ws_size,
                              hipStream_t stream)
{
  const int*   recipe = (const int*)d_in[0];
  const int*   g      = (const int*)d_in[1];
  const int*   ingr   = (const int*)d_in[2];
  const float* wv     = (const float*)d_in[3];
  const float* w_ih   = (const float*)d_in[4];
  const float* w_hh   = (const float*)d_in[5];
  const float* b_ih   = (const float*)d_in[6];
  const float* b_hh   = (const float*)d_in[7];
  const float* Z      = (const float*)d_in[8];
  const float* Y      = (const float*)d_in[9];
  const float* Ug     = (const float*)d_in[10];
  const float* z_bias = (const float*)d_in[11];
  const float* y_bias = (const float*)d_in[12];
  const float* S      = (const float*)d_in[13];
  const float* P      = (const float*)d_in[14];
  const float* fcW    = (const float*)d_in[15];
  const float* fcb    = (const float*)d_in[16];
  float* out = (float*)d_out;
  char* ws = (char*)d_ws;

  size_t off = 0;
  double* XBH              = (double*)(ws + off);          off += 65536;
  double* XBP              = (double*)(ws + off);          off += 532480;
  unsigned short* wv_b     = (unsigned short*)(ws + off);  off += 16384000;
  unsigned short* wih_b    = (unsigned short*)(ws + off);  off += 655360;
  unsigned short* fcw_b    = (unsigned short*)(ws + off);  off += 16384000;
  unsigned short* whh_f    = (unsigned short*)(ws + off);  off += 655360;
  unsigned short* z_f      = (unsigned short*)(ws + off);  off += 131072;
  unsigned short* p_f      = (unsigned short*)(ws + off);  off += 131072;
  float* gi_ws             = (float*)(ws + off);           off += 10485760;
  float* E_ws              = (float*)(ws + off);           off += 819200;
  float* sumE              = (float*)(ws + off);           off += 16384;
  float* goal_ws           = (float*)(ws + off);           off += 16384;
  float* HT0               = (float*)(ws + off);           off += 16384;
  unsigned short* out_all  = (unsigned short*)(ws + off);  off += 1048576;

  hipMemsetAsync(XBH, 0, 65536 + 532480, stream);   // tags=0: replay-safe
  conv_kernel<<<4096, 256, 0, stream>>>(wv, w_ih, fcW, w_hh, Z, P,
                                        wv_b, wih_b, fcw_b, whh_f, z_f, p_f);
  prep_kernel<<<16, 256, 0, stream>>>(g, ingr, wv, Ug, Y, y_bias,
                                      E_ws, sumE, goal_ws, HT0);
  gemm_bf16<0><<<dim3(16, 10), 256, 0, stream>>>(wv_b, wih_b, recipe, b_ih, gi_ws);
  hipFuncSetAttribute((const void*)rnn_kernel,
                      hipFuncAttributeMaxDynamicSharedMemorySize, RNN_SMEM);
  rnn_kernel<<<128, 256, RNN_SMEM, stream>>>(whh_f, z_f, p_f, b_hh, S, z_bias,
                                             gi_ws, goal_ws, E_ws, sumE, HT0,
                                             out_all, out, XBH, XBP);
  gemm_bf16<1><<<dim3(16, 250), 256, 0, stream>>>(out_all, fcw_b, nullptr, fcb, out);
}